// Round 3
// baseline (324.163 us; speedup 1.0000x reference)
//
#include <hip/hip_runtime.h>

// SimpleAttentionLayer: out[b,n,s] = softmax_s( sum_k tanh(enc[s,b,n,:]·W[k,:] + b[k]) * dec[b,n,k] )
// S=64, B=32, N=325, H=64. fp32 throughout.
//
// One wave per (b,n); lane = s.
// Round 1/2 lesson: holding the 64-float enc row live loses — the RA targets
// 8 waves/SIMD (64 VGPR) and spills load-only values to scratch, leaving the
// k-loop VMEM-latency-bound (VALUBusy 34%, dur 150us). This version flips the
// structure: the 64 per-k ACCUMULATORS are the big live set (loop-carried,
// read-modify-write -> RA must keep them), and enc is consumed in 16-float
// chunks. amdgpu_waves_per_eu(4,4) pins the RA budget at 128 VGPRs.

constexpr int S = 64, B = 32, N = 325, H = 64;
constexpr int BN = B * N;  // 10400

__global__ __launch_bounds__(256)
__attribute__((amdgpu_waves_per_eu(4, 4)))
void attn_fused(
    const float* __restrict__ enc,   // (S,B,N,H)
    const float* __restrict__ dec,   // (B,N,H)
    const float* __restrict__ W,     // (H,H)
    const float* __restrict__ bias,  // (H)
    float* __restrict__ out)         // (B,N,S)
{
    const int lane = threadIdx.x & 63;                                   // s
    const int wave = __builtin_amdgcn_readfirstlane(threadIdx.x >> 6);
    const int bn   = blockIdx.x * 4 + wave;                              // wave-uniform

    const float* erow = enc + (lane * BN + bn) * H;   // this lane's enc row
    const float* drow = dec + bn * H;                 // wave-uniform

    float acc[64];
#pragma unroll
    for (int k = 0; k < 64; ++k) acc[k] = 0.0f;

    // h in 4 chunks of 16; acc[64] carried across chunks (forces residency)
    for (int hc = 0; hc < 4; ++hc) {
        const float4* ep = (const float4*)(erow + hc * 16);
        float4 e0 = ep[0], e1 = ep[1], e2 = ep[2], e3 = ep[3];
#pragma unroll
        for (int k = 0; k < 64; ++k) {
            const float4* wr = (const float4*)(W + k * H + hc * 16);  // uniform -> s_load
            float4 w0 = wr[0], w1 = wr[1], w2 = wr[2], w3 = wr[3];
            // two independent 8-FMA chains per k (cover 4cy FMA latency)
            float a = fmaf(e0.x, w0.x, acc[k]);
            float c = e0.y * w0.y;
            a = fmaf(e0.z, w0.z, a);   c = fmaf(e0.w, w0.w, c);
            a = fmaf(e1.x, w1.x, a);   c = fmaf(e1.y, w1.y, c);
            a = fmaf(e1.z, w1.z, a);   c = fmaf(e1.w, w1.w, c);
            a = fmaf(e2.x, w2.x, a);   c = fmaf(e2.y, w2.y, c);
            a = fmaf(e2.z, w2.z, a);   c = fmaf(e2.w, w2.w, c);
            a = fmaf(e3.x, w3.x, a);   c = fmaf(e3.y, w3.y, c);
            a = fmaf(e3.z, w3.z, a);   c = fmaf(e3.w, w3.w, c);
            acc[k] = a + c;
        }
    }

    // epilogue: e_s = sum_k tanh(acc[k] + bias[k]) * dec[k]   (bias/dec uniform)
    float e_s = 0.0f;
#pragma unroll
    for (int k = 0; k < 64; ++k) {
        float a  = acc[k] + bias[k];
        float t  = __expf(2.0f * a);                       // tanh = 1 - 2/(e^2a+1)
        float th = 1.0f - 2.0f * __builtin_amdgcn_rcpf(t + 1.0f);
        e_s = fmaf(th, drow[k], e_s);
    }

    // softmax over s = the 64 lanes of this wave
    float m = e_s;
#pragma unroll
    for (int off = 32; off > 0; off >>= 1)
        m = fmaxf(m, __shfl_xor(m, off, 64));
    float p = __expf(e_s - m);
    float sum = p;
#pragma unroll
    for (int off = 32; off > 0; off >>= 1)
        sum += __shfl_xor(sum, off, 64);

    out[bn * S + lane] = p * __builtin_amdgcn_rcpf(sum);
}

extern "C" void kernel_launch(void* const* d_in, const int* in_sizes, int n_in,
                              void* d_out, int out_size, void* d_ws, size_t ws_size,
                              hipStream_t stream) {
    const float* enc  = (const float*)d_in[0];
    const float* dec  = (const float*)d_in[1];
    const float* W    = (const float*)d_in[2];
    const float* bias = (const float*)d_in[3];
    float* out        = (float*)d_out;

    dim3 grid(BN / 4);   // 2600 blocks x 4 waves = 10400 waves = one per (b,n)
    attn_fused<<<grid, 256, 0, stream>>>(enc, dec, W, bias, out);
}

// Round 4
// 263.793 us; speedup vs baseline: 1.2289x; 1.2289x over previous
//
#include <hip/hip_runtime.h>

// out[b,n,s] = softmax_s( sum_k tanh(enc[s,b,n,:]·W[k,:] + b[k]) * dec[b,n,k] )
// S=64, B=32, N=325, H=64, fp32.
//
// Rounds 1-3: scalar-FMA versions all plateau at ~150us because the RA refuses
// to keep a 64-float/lane working set (VGPR count 44/48/52, spills to scratch).
// This version moves the 64x64x64 per-bn GEMM onto MFMA (16x16x32 bf16) with a
// split-bf16 hi/lo decomposition for fp32-level accuracy:
//   x = hi + lo (truncation split, residual exact);  a·b ≈ ah·bh + al·bh + ah·bl
// 3x MFMA count ~ 7us of matrix pipe vs 27us HBM floor for enc (170 MB).
// One wave per bn; epilogue transposes the C-layout P-slab through a
// wave-private LDS region (no __syncthreads anywhere).

constexpr int S = 64, B = 32, N = 325, H = 64;
constexpr int BN = B * N;  // 10400

typedef __attribute__((ext_vector_type(8))) short short8;  // 8 bf16 = 4 VGPRs
typedef __attribute__((ext_vector_type(4))) float f32x4;

union FragU { unsigned u[4]; short8 s8; };

// truncation split: returns packed (bf16(x0),bf16(x1)) hi pair, residuals out
__device__ inline unsigned pack_hi(float x0, float x1, float& r0, float& r1) {
    unsigned u0 = __builtin_bit_cast(unsigned, x0);
    unsigned u1 = __builtin_bit_cast(unsigned, x1);
    r0 = x0 - __builtin_bit_cast(float, u0 & 0xffff0000u);  // exact
    r1 = x1 - __builtin_bit_cast(float, u1 & 0xffff0000u);
    return (u0 >> 16) | (u1 & 0xffff0000u);
}
__device__ inline unsigned pack_bf(float x0, float x1) {
    return (__builtin_bit_cast(unsigned, x0) >> 16) |
           (__builtin_bit_cast(unsigned, x1) & 0xffff0000u);
}

__global__ __launch_bounds__(256) void attn_mfma(
    const float* __restrict__ enc,   // (S,B,N,H)
    const float* __restrict__ dec,   // (B,N,H)
    const float* __restrict__ W,     // (H,H)
    const float* __restrict__ bias,  // (H)
    float* __restrict__ out)         // (B,N,S)
{
    const int lane = threadIdx.x & 63;
    const int wv   = threadIdx.x >> 6;
    const int bn   = blockIdx.x * 4 + wv;        // wave-uniform
    const int col  = lane & 15;                  // tile col (n) / kout_local / m
    const int grp  = lane >> 4;                  // quad

    __shared__ float P[4][16 * 65];              // per-wave [k_local][s] slab, +1 pad
    float* Pw = P[wv];

    // per-lane epilogue constants: lane owns column kout = q*16+col
    float bias_v[4], dec_v[4];
#pragma unroll
    for (int q = 0; q < 4; ++q) {
        bias_v[q] = bias[q * 16 + col];
        dec_v[q]  = dec[bn * H + q * 16 + col];
    }

    // ---- A fragments: enc rows in MFMA A-layout, split hi/lo ----
    // A[m][k]: m = lane&15 (+16*mt), k = grp*8 + j (+32*kc)
    FragU a_hi[4][2], a_lo[4][2];
#pragma unroll
    for (int mt = 0; mt < 4; ++mt) {
        const float* er = enc + ((mt * 16 + col) * BN + bn) * H;
#pragma unroll
        for (int kc = 0; kc < 2; ++kc) {
            const float4* p4 = (const float4*)(er + kc * 32 + grp * 8);
            float4 x0 = p4[0], x1 = p4[1];
            float r0, r1, r2, r3, r4, r5, r6, r7;
            a_hi[mt][kc].u[0] = pack_hi(x0.x, x0.y, r0, r1);
            a_hi[mt][kc].u[1] = pack_hi(x0.z, x0.w, r2, r3);
            a_hi[mt][kc].u[2] = pack_hi(x1.x, x1.y, r4, r5);
            a_hi[mt][kc].u[3] = pack_hi(x1.z, x1.w, r6, r7);
            a_lo[mt][kc].u[0] = pack_bf(r0, r1);
            a_lo[mt][kc].u[1] = pack_bf(r2, r3);
            a_lo[mt][kc].u[2] = pack_bf(r4, r5);
            a_lo[mt][kc].u[3] = pack_bf(r6, r7);
        }
    }

    float e_s = 0.0f;

    for (int q = 0; q < 4; ++q) {                // kout in quarters of 16
        f32x4 acc[4];
#pragma unroll
        for (int mt = 0; mt < 4; ++mt) acc[mt] = (f32x4){0.f, 0.f, 0.f, 0.f};

#pragma unroll
        for (int kc = 0; kc < 2; ++kc) {
            // B[k][n] = W[kout][h]: n = col -> kout=q*16+col, k = grp*8+j -> h
            const float4* wp = (const float4*)(W + (q * 16 + col) * H + kc * 32 + grp * 8);
            float4 w0 = wp[0], w1 = wp[1];
            float r0, r1, r2, r3, r4, r5, r6, r7;
            FragU b_hi, b_lo;
            b_hi.u[0] = pack_hi(w0.x, w0.y, r0, r1);
            b_hi.u[1] = pack_hi(w0.z, w0.w, r2, r3);
            b_hi.u[2] = pack_hi(w1.x, w1.y, r4, r5);
            b_hi.u[3] = pack_hi(w1.z, w1.w, r6, r7);
            b_lo.u[0] = pack_bf(r0, r1);
            b_lo.u[1] = pack_bf(r2, r3);
            b_lo.u[2] = pack_bf(r4, r5);
            b_lo.u[3] = pack_bf(r6, r7);
#pragma unroll
            for (int mt = 0; mt < 4; ++mt) {
                acc[mt] = __builtin_amdgcn_mfma_f32_16x16x32_bf16(a_hi[mt][kc].s8, b_hi.s8, acc[mt], 0, 0, 0);
                acc[mt] = __builtin_amdgcn_mfma_f32_16x16x32_bf16(a_lo[mt][kc].s8, b_hi.s8, acc[mt], 0, 0, 0);
                acc[mt] = __builtin_amdgcn_mfma_f32_16x16x32_bf16(a_hi[mt][kc].s8, b_lo.s8, acc[mt], 0, 0, 0);
            }
        }

        // epilogue for this kout quarter: tanh, scale by dec, stage P[k][s] in LDS
        // C/D layout: col = lane&15 (= kout_local), row = grp*4 + reg (= s_local)
#pragma unroll
        for (int mt = 0; mt < 4; ++mt) {
#pragma unroll
            for (int r = 0; r < 4; ++r) {
                int s   = mt * 16 + grp * 4 + r;
                float a = acc[mt][r] + bias_v[q];
                float t = 1.0f - 2.0f * __builtin_amdgcn_rcpf(__expf(2.0f * a) + 1.0f);
                Pw[col * 65 + s] = t * dec_v[q];
            }
        }
        // same-wave LDS round-trip (compiler inserts lgkmcnt); no barrier needed
#pragma unroll
        for (int k = 0; k < 16; ++k)
            e_s += Pw[k * 65 + lane];            // lane = s
    }

    // softmax over s = 64 lanes
    float m = e_s;
#pragma unroll
    for (int off = 32; off > 0; off >>= 1)
        m = fmaxf(m, __shfl_xor(m, off, 64));
    float p = __expf(e_s - m);
    float sum = p;
#pragma unroll
    for (int off = 32; off > 0; off >>= 1)
        sum += __shfl_xor(sum, off, 64);

    out[bn * S + lane] = p * __builtin_amdgcn_rcpf(sum);
}

extern "C" void kernel_launch(void* const* d_in, const int* in_sizes, int n_in,
                              void* d_out, int out_size, void* d_ws, size_t ws_size,
                              hipStream_t stream) {
    const float* enc  = (const float*)d_in[0];
    const float* dec  = (const float*)d_in[1];
    const float* W    = (const float*)d_in[2];
    const float* bias = (const float*)d_in[3];
    float* out        = (float*)d_out;

    dim3 grid(BN / 4);   // 2600 blocks x 4 waves = one wave per (b,n)
    attn_mfma<<<grid, 256, 0, stream>>>(enc, dec, W, bias, out);
}

// Round 5
// 257.871 us; speedup vs baseline: 1.2571x; 1.0230x over previous
//
#include <hip/hip_runtime.h>

// out[b,n,s] = softmax_s( sum_k tanh(enc[s,b,n,:]·W[k,:] + b[k]) * dec[b,n,k] )
// S=64, B=32, N=325, H=64, fp32. Split-bf16 MFMA (hi/lo truncation split,
// 3-term: ah·bh + al·bh + ah·bl) for fp32-level accuracy on 16x16x32 bf16 MFMA.
//
// R4 (one wave per bn, 64 VGPR of A-frags live): ~95us, ~3x above cost model —
// register-pressure/latency bound. R5: each bn split across 2 waves (32 s each,
// A-frags 32 VGPR -> ~6 waves/SIMD), W B-fragments pre-packed once into ws by a
// prep kernel (kills 320 pack-VALU/wave), softmax halves joined via LDS +
// one __syncthreads.

constexpr int S = 64, B = 32, N = 325, H = 64;
constexpr int BN = B * N;  // 10400

typedef __attribute__((ext_vector_type(8))) short short8;  // 8 bf16
typedef __attribute__((ext_vector_type(4))) float f32x4;

union FragU { unsigned u[4]; short8 s8; uint4 v4; };

__device__ inline unsigned pack_hi(float x0, float x1, float& r0, float& r1) {
    unsigned u0 = __builtin_bit_cast(unsigned, x0);
    unsigned u1 = __builtin_bit_cast(unsigned, x1);
    r0 = x0 - __builtin_bit_cast(float, u0 & 0xffff0000u);  // exact residual
    r1 = x1 - __builtin_bit_cast(float, u1 & 0xffff0000u);
    return (u0 >> 16) | (u1 & 0xffff0000u);
}
__device__ inline unsigned pack_bf(float x0, float x1) {
    return (__builtin_bit_cast(unsigned, x0) >> 16) |
           (__builtin_bit_cast(unsigned, x1) & 0xffff0000u);
}

// ---- prep: pack W into per-lane MFMA B-fragments (hi/lo), 16 KB into ws ----
// layout: wp[((q*2+kc)*2 + {0=hi,1=lo})*64 + lane] : uint4
__global__ void pack_w(const float* __restrict__ W, uint4* __restrict__ wp) {
    int idx  = blockIdx.x * blockDim.x + threadIdx.x;   // 512 threads
    if (idx >= 512) return;
    int q    = idx >> 7;
    int kc   = (idx >> 6) & 1;
    int lane = idx & 63;
    int col  = lane & 15, grp = lane >> 4;
    const float4* wpt = (const float4*)(W + (q * 16 + col) * H + kc * 32 + grp * 8);
    float4 w0 = wpt[0], w1 = wpt[1];
    float r0, r1, r2, r3, r4, r5, r6, r7;
    FragU hi, lo;
    hi.u[0] = pack_hi(w0.x, w0.y, r0, r1);
    hi.u[1] = pack_hi(w0.z, w0.w, r2, r3);
    hi.u[2] = pack_hi(w1.x, w1.y, r4, r5);
    hi.u[3] = pack_hi(w1.z, w1.w, r6, r7);
    lo.u[0] = pack_bf(r0, r1);
    lo.u[1] = pack_bf(r2, r3);
    lo.u[2] = pack_bf(r4, r5);
    lo.u[3] = pack_bf(r6, r7);
    wp[((q * 2 + kc) * 2 + 0) * 64 + lane] = hi.v4;
    wp[((q * 2 + kc) * 2 + 1) * 64 + lane] = lo.v4;
}

// ---- main: block = 4 waves = 2 bn; each wave does 32 s x 64 kout ----
__global__ __launch_bounds__(256) void attn_mfma2(
    const float* __restrict__ enc,   // (S,B,N,H)
    const float* __restrict__ dec,   // (B,N,H)
    const float* __restrict__ bias,  // (H)
    const uint4* __restrict__ wp,    // packed W frags (ws)
    float* __restrict__ out)         // (B,N,S)
{
    const int lane  = threadIdx.x & 63;
    const int wv    = threadIdx.x >> 6;
    const int bnl   = wv >> 1;            // which bn of the block's pair
    const int shalf = wv & 1;             // which 32-s half
    const int bn    = blockIdx.x * 2 + bnl;
    const int col   = lane & 15;
    const int grp   = lane >> 4;

    __shared__ float P[4][16 * 33];       // per-wave [k_local][s_local] slab, +1 pad
    __shared__ float eS[2][64];           // per-bn e vector
    float* Pw = P[wv];

    float bias_v[4], dec_v[4];
#pragma unroll
    for (int q = 0; q < 4; ++q) {
        bias_v[q] = bias[q * 16 + col];
        dec_v[q]  = dec[bn * H + q * 16 + col];
    }

    // A fragments for this wave's 32 s rows (A[m][k]: m=lane&15, k=grp*8+j)
    FragU a_hi[2][2], a_lo[2][2];
#pragma unroll
    for (int mt = 0; mt < 2; ++mt) {
        const float* er = enc + (((shalf * 2 + mt) * 16 + col) * BN + bn) * H;
#pragma unroll
        for (int kc = 0; kc < 2; ++kc) {
            const float4* p4 = (const float4*)(er + kc * 32 + grp * 8);
            float4 x0 = p4[0], x1 = p4[1];
            float r0, r1, r2, r3, r4, r5, r6, r7;
            a_hi[mt][kc].u[0] = pack_hi(x0.x, x0.y, r0, r1);
            a_hi[mt][kc].u[1] = pack_hi(x0.z, x0.w, r2, r3);
            a_hi[mt][kc].u[2] = pack_hi(x1.x, x1.y, r4, r5);
            a_hi[mt][kc].u[3] = pack_hi(x1.z, x1.w, r6, r7);
            a_lo[mt][kc].u[0] = pack_bf(r0, r1);
            a_lo[mt][kc].u[1] = pack_bf(r2, r3);
            a_lo[mt][kc].u[2] = pack_bf(r4, r5);
            a_lo[mt][kc].u[3] = pack_bf(r6, r7);
        }
    }

    float e_s = 0.0f;
#pragma unroll
    for (int q = 0; q < 4; ++q) {
        f32x4 acc[2];
#pragma unroll
        for (int mt = 0; mt < 2; ++mt) acc[mt] = (f32x4){0.f, 0.f, 0.f, 0.f};

#pragma unroll
        for (int kc = 0; kc < 2; ++kc) {
            FragU bh, bl;
            bh.v4 = wp[((q * 2 + kc) * 2 + 0) * 64 + lane];
            bl.v4 = wp[((q * 2 + kc) * 2 + 1) * 64 + lane];
#pragma unroll
            for (int mt = 0; mt < 2; ++mt) {
                acc[mt] = __builtin_amdgcn_mfma_f32_16x16x32_bf16(a_hi[mt][kc].s8, bh.s8, acc[mt], 0, 0, 0);
                acc[mt] = __builtin_amdgcn_mfma_f32_16x16x32_bf16(a_lo[mt][kc].s8, bh.s8, acc[mt], 0, 0, 0);
                acc[mt] = __builtin_amdgcn_mfma_f32_16x16x32_bf16(a_hi[mt][kc].s8, bl.s8, acc[mt], 0, 0, 0);
            }
        }

        // epilogue for this kout quarter (C/D: col=lane&15 -> kout, row=grp*4+r -> s)
#pragma unroll
        for (int mt = 0; mt < 2; ++mt) {
#pragma unroll
            for (int r = 0; r < 4; ++r) {
                int sl  = mt * 16 + grp * 4 + r;   // 0..31
                float a = acc[mt][r] + bias_v[q];
                float t = 1.0f - 2.0f * __builtin_amdgcn_rcpf(__expf(2.0f * a) + 1.0f);
                Pw[col * 33 + sl] = t * dec_v[q];
            }
        }
        // wave-private LDS transpose: sum over the 16 kout of this quarter
#pragma unroll
        for (int k = 0; k < 16; ++k)
            e_s += Pw[k * 33 + (lane & 31)];
    }

    // join the two s-halves of this bn, then softmax over all 64 s
    if (lane < 32) eS[bnl][shalf * 32 + lane] = e_s;
    __syncthreads();
    float ev = eS[bnl][lane];

    float m = ev;
#pragma unroll
    for (int off = 32; off > 0; off >>= 1)
        m = fmaxf(m, __shfl_xor(m, off, 64));
    float p = __expf(ev - m);
    float sum = p;
#pragma unroll
    for (int off = 32; off > 0; off >>= 1)
        sum += __shfl_xor(sum, off, 64);

    if (shalf == 0)
        out[bn * S + lane] = p * __builtin_amdgcn_rcpf(sum);
}

extern "C" void kernel_launch(void* const* d_in, const int* in_sizes, int n_in,
                              void* d_out, int out_size, void* d_ws, size_t ws_size,
                              hipStream_t stream) {
    const float* enc  = (const float*)d_in[0];
    const float* dec  = (const float*)d_in[1];
    const float* W    = (const float*)d_in[2];
    const float* bias = (const float*)d_in[3];
    float* out        = (float*)d_out;

    pack_w<<<2, 256, 0, stream>>>(W, (uint4*)d_ws);
    attn_mfma2<<<BN / 2, 256, 0, stream>>>(enc, dec, bias, (const uint4*)d_ws, out);
}

// Round 6
// 254.818 us; speedup vs baseline: 1.2721x; 1.0120x over previous
//
#include <hip/hip_runtime.h>

// out[b,n,s] = softmax_s( sum_k tanh(enc[s,b,n,:]·W[k,:] + b[k]) * dec[b,n,k] )
// S=64, B=32, N=325, H=64, fp32. Split-bf16 MFMA (3-term ah·bh+al·bh+ah·bl).
//
// R4/R5 (~91-96us) mapped waves to (s,bn): every enc load was a 16-way scatter
// over rows strided 2,662,400 B (= 650*4KiB -> identical low addr bits), and a
// ~110-op LDS transpose epilogue per wave. R6 flattens: energy kernel treats
// enc as a dense (665600 x 64) matrix; MFMA tiles cover 16 CONSECUTIVE rows so
// A-loads are contiguous 1KB/instr streams. dec-dot finished with shfl_xor
// butterfly (no LDS, no barrier). Softmax moved to a tiny tiled second kernel.

constexpr int S = 64, B = 32, N = 325, H = 64;
constexpr int BN = B * N;        // 10400
constexpr int SBN = S * BN;      // 665600

typedef __attribute__((ext_vector_type(8))) short short8;  // 8 bf16
typedef __attribute__((ext_vector_type(4))) float f32x4;

union FragU { unsigned u[4]; short8 s8; uint4 v4; };

__device__ inline unsigned pack_hi(float x0, float x1, float& r0, float& r1) {
    unsigned u0 = __builtin_bit_cast(unsigned, x0);
    unsigned u1 = __builtin_bit_cast(unsigned, x1);
    r0 = x0 - __builtin_bit_cast(float, u0 & 0xffff0000u);  // exact residual
    r1 = x1 - __builtin_bit_cast(float, u1 & 0xffff0000u);
    return (u0 >> 16) | (u1 & 0xffff0000u);
}
__device__ inline unsigned pack_bf(float x0, float x1) {
    return (__builtin_bit_cast(unsigned, x0) >> 16) |
           (__builtin_bit_cast(unsigned, x1) & 0xffff0000u);
}

// ---- prep: W -> per-lane MFMA B-fragments (hi/lo), 16 KB at ws+0 ----
__global__ void pack_w(const float* __restrict__ W, uint4* __restrict__ wp) {
    int idx = blockIdx.x * blockDim.x + threadIdx.x;
    if (idx >= 512) return;
    int q = idx >> 7, kc = (idx >> 6) & 1, lane = idx & 63;
    int col = lane & 15, grp = lane >> 4;
    const float4* wpt = (const float4*)(W + (q * 16 + col) * H + kc * 32 + grp * 8);
    float4 w0 = wpt[0], w1 = wpt[1];
    float r0, r1, r2, r3, r4, r5, r6, r7;
    FragU hi, lo;
    hi.u[0] = pack_hi(w0.x, w0.y, r0, r1);
    hi.u[1] = pack_hi(w0.z, w0.w, r2, r3);
    hi.u[2] = pack_hi(w1.x, w1.y, r4, r5);
    hi.u[3] = pack_hi(w1.z, w1.w, r6, r7);
    lo.u[0] = pack_bf(r0, r1); lo.u[1] = pack_bf(r2, r3);
    lo.u[2] = pack_bf(r4, r5); lo.u[3] = pack_bf(r6, r7);
    wp[((q * 2 + kc) * 2 + 0) * 64 + lane] = hi.v4;
    wp[((q * 2 + kc) * 2 + 1) * 64 + lane] = lo.v4;
}

// ---- kernel A: e[sbn] = sum_k tanh(enc[sbn,:]·W[k,:]+b[k]) * dec[sbn%BN, k] ----
// wave handles 32 consecutive rows (2 MFMA m-tiles); no LDS, no barrier.
__global__ __launch_bounds__(256) void energy_k(
    const float* __restrict__ enc, const float* __restrict__ dec,
    const float* __restrict__ bias, const uint4* __restrict__ wp,
    float* __restrict__ e)
{
    const int lane = threadIdx.x & 63;
    const int wv   = threadIdx.x >> 6;
    const int col  = lane & 15, grp = lane >> 4;
    const int row0 = (blockIdx.x * 4 + wv) * 32;   // 5200 blocks * 4 waves * 32 rows

    // A fragments: 16 consecutive rows per tile -> contiguous 4KB per (mt)
    FragU a_hi[2][2], a_lo[2][2];
#pragma unroll
    for (int mt = 0; mt < 2; ++mt) {
        const float* er = enc + (row0 + mt * 16 + col) * H;
#pragma unroll
        for (int kc = 0; kc < 2; ++kc) {
            const float4* p4 = (const float4*)(er + kc * 32 + grp * 8);
            float4 x0 = p4[0], x1 = p4[1];
            float r0, r1, r2, r3, r4, r5, r6, r7;
            a_hi[mt][kc].u[0] = pack_hi(x0.x, x0.y, r0, r1);
            a_hi[mt][kc].u[1] = pack_hi(x0.z, x0.w, r2, r3);
            a_hi[mt][kc].u[2] = pack_hi(x1.x, x1.y, r4, r5);
            a_hi[mt][kc].u[3] = pack_hi(x1.z, x1.w, r6, r7);
            a_lo[mt][kc].u[0] = pack_bf(r0, r1);
            a_lo[mt][kc].u[1] = pack_bf(r2, r3);
            a_lo[mt][kc].u[2] = pack_bf(r4, r5);
            a_lo[mt][kc].u[3] = pack_bf(r6, r7);
        }
    }

    // per-(mt,r) row index -> bn -> dec offset (col gives the kout lane)
    int doff[2][4];
#pragma unroll
    for (int mt = 0; mt < 2; ++mt)
#pragma unroll
        for (int r = 0; r < 4; ++r) {
            unsigned sbn = (unsigned)(row0 + mt * 16 + grp * 4 + r);
            unsigned bn  = sbn % (unsigned)BN;     // magic-mul, ~4 VALU
            doff[mt][r]  = (int)(bn * H) + col;
        }

    float bias_v[4];
#pragma unroll
    for (int q = 0; q < 4; ++q) bias_v[q] = bias[q * 16 + col];

    float part[2][4];
#pragma unroll
    for (int mt = 0; mt < 2; ++mt)
#pragma unroll
        for (int r = 0; r < 4; ++r) part[mt][r] = 0.0f;

#pragma unroll
    for (int q = 0; q < 4; ++q) {
        f32x4 acc[2];
        acc[0] = (f32x4){0.f, 0.f, 0.f, 0.f};
        acc[1] = (f32x4){0.f, 0.f, 0.f, 0.f};
#pragma unroll
        for (int kc = 0; kc < 2; ++kc) {
            FragU bh, bl;
            bh.v4 = wp[((q * 2 + kc) * 2 + 0) * 64 + lane];
            bl.v4 = wp[((q * 2 + kc) * 2 + 1) * 64 + lane];
#pragma unroll
            for (int mt = 0; mt < 2; ++mt) {
                acc[mt] = __builtin_amdgcn_mfma_f32_16x16x32_bf16(a_hi[mt][kc].s8, bh.s8, acc[mt], 0, 0, 0);
                acc[mt] = __builtin_amdgcn_mfma_f32_16x16x32_bf16(a_lo[mt][kc].s8, bh.s8, acc[mt], 0, 0, 0);
                acc[mt] = __builtin_amdgcn_mfma_f32_16x16x32_bf16(a_hi[mt][kc].s8, bl.s8, acc[mt], 0, 0, 0);
            }
        }
        // C/D layout: lane holds energy[m = grp*4+r (+16mt)][kout = q*16+col]
#pragma unroll
        for (int mt = 0; mt < 2; ++mt)
#pragma unroll
            for (int r = 0; r < 4; ++r) {
                float a = acc[mt][r] + bias_v[q];
                float t = 1.0f - 2.0f * __builtin_amdgcn_rcpf(__expf(2.0f * a) + 1.0f);
                part[mt][r] = fmaf(t, dec[doff[mt][r] + q * 16], part[mt][r]);
            }
    }

    // reduce over the 16 kout-lanes (xor bits 0-3 stay within the 16-group)
#pragma unroll
    for (int mt = 0; mt < 2; ++mt)
#pragma unroll
        for (int r = 0; r < 4; ++r) {
            float v = part[mt][r];
            v += __shfl_xor(v, 1, 64);
            v += __shfl_xor(v, 2, 64);
            v += __shfl_xor(v, 4, 64);
            v += __shfl_xor(v, 8, 64);
            part[mt][r] = v;
        }

    // lanes col<8 store: value index sel = col&7 -> (mt = col>>2, r = col&3)
    float va = (col & 1) ? part[0][1] : part[0][0];
    float vb = (col & 1) ? part[0][3] : part[0][2];
    float vc = (col & 1) ? part[1][1] : part[1][0];
    float vd = (col & 1) ? part[1][3] : part[1][2];
    float ve = (col & 2) ? vb : va;
    float vf = (col & 2) ? vd : vc;
    float vo = (col & 4) ? vf : ve;
    if (col < 8)
        e[row0 + ((col >> 2) & 1) * 16 + grp * 4 + (col & 3)] = vo;
}

// ---- kernel B: softmax over s per bn; 64bn x 64s LDS tile, coalesced both ways
__global__ __launch_bounds__(256) void softmax_k(
    const float* __restrict__ e,    // (S, BN)
    float* __restrict__ out)        // (BN, S)
{
    __shared__ float Et[64 * 65];
    __shared__ float Mred[4][64], Sred[4][64], Mfin[64], Rfin[64];

    const int t = threadIdx.x;
    const int bn0 = blockIdx.x * 64;
    const int lane = t & 63, w = t >> 6;

    // stage: Et[s][bn_loc], reads of e coalesced along bn
#pragma unroll
    for (int i = 0; i < 16; ++i) {
        int s = w * 16 + i;
        float v = (bn0 + lane < BN) ? e[s * BN + bn0 + lane] : 0.0f;
        Et[s * 65 + lane] = v;
    }
    __syncthreads();

    // per-bn max then sum(exp), 4 threads per bn
    {
        const int bn_loc = t & 63, sq = t >> 6;
        float m = -1e30f;
#pragma unroll
        for (int i = 0; i < 16; ++i)
            m = fmaxf(m, Et[(sq * 16 + i) * 65 + bn_loc]);
        Mred[sq][bn_loc] = m;
    }
    __syncthreads();
    {
        const int bn_loc = t & 63, sq = t >> 6;
        float m = fmaxf(fmaxf(Mred[0][bn_loc], Mred[1][bn_loc]),
                        fmaxf(Mred[2][bn_loc], Mred[3][bn_loc]));
        float sum = 0.0f;
#pragma unroll
        for (int i = 0; i < 16; ++i)
            sum += __expf(Et[(sq * 16 + i) * 65 + bn_loc] - m);
        Sred[sq][bn_loc] = sum;
        if (sq == 0) Mfin[bn_loc] = m;
    }
    __syncthreads();
    if ((t >> 6) == 0) {
        const int bn_loc = t & 63;
        float sum = Sred[0][bn_loc] + Sred[1][bn_loc] + Sred[2][bn_loc] + Sred[3][bn_loc];
        Rfin[bn_loc] = __builtin_amdgcn_rcpf(sum);
    }
    __syncthreads();

    // write out[bn][s], lanes -> s (coalesced)
    const int s_out = t & 63, bq = t >> 6;
#pragma unroll
    for (int j = 0; j < 16; ++j) {
        int bn_loc = bq * 16 + j;
        if (bn0 + bn_loc < BN) {
            float p = __expf(Et[s_out * 65 + bn_loc] - Mfin[bn_loc]) * Rfin[bn_loc];
            out[(bn0 + bn_loc) * S + s_out] = p;
        }
    }
}

extern "C" void kernel_launch(void* const* d_in, const int* in_sizes, int n_in,
                              void* d_out, int out_size, void* d_ws, size_t ws_size,
                              hipStream_t stream) {
    const float* enc  = (const float*)d_in[0];
    const float* dec  = (const float*)d_in[1];
    const float* W    = (const float*)d_in[2];
    const float* bias = (const float*)d_in[3];
    float* out        = (float*)d_out;

    uint4* wp = (uint4*)d_ws;                          // 16 KB
    float* e  = (float*)((char*)d_ws + 65536);         // 2.66 MB

    pack_w<<<2, 256, 0, stream>>>(W, wp);
    energy_k<<<SBN / 128, 256, 0, stream>>>(enc, dec, bias, wp, e);  // 5200 blocks
    softmax_k<<<(BN + 63) / 64, 256, 0, stream>>>(e, out);           // 163 blocks
}